// Round 4
// baseline (175.152 us; speedup 1.0000x reference)
//
#include <hip/hip_runtime.h>
#include <hip/hip_bf16.h>
#include <stdint.h>

#define M_TOT 16384
#define K_TOT 4096
#define N_COLS 4096
#define NS 409
#define NP 448            // padded N: 4 waves x 7 frags x 16
#define BM 64
#define BK 64
#define NT (K_TOT / BK)   // 64

#define BS_BYTES (NP * BK * 2)                    // 57344
#define AS_BYTES (BM * BK * 2)                    // 8192 (A as bf16 now)
#define LDS_TOTAL (2 * BS_BYTES + 2 * AS_BYTES)   // 131072

typedef __attribute__((ext_vector_type(4))) float f32x4;
typedef __attribute__((ext_vector_type(8))) short bf16x8;
typedef __attribute__((ext_vector_type(8))) unsigned short u16x8;

#define VMWAIT(N) asm volatile("s_waitcnt vmcnt(" #N ")" ::: "memory")
#define FULLWAIT() asm volatile("s_waitcnt vmcnt(0) lgkmcnt(0)" ::: "memory")
#define LGKM0() asm volatile("s_waitcnt lgkmcnt(0)" ::: "memory")
#define BAR() do { __builtin_amdgcn_s_barrier(); asm volatile("" ::: "memory"); } while (0)

__device__ inline unsigned short f2bf(float f) {
  unsigned u = __float_as_uint(f);
  u += 0x7FFFu + ((u >> 16) & 1u);  // RNE
  return (unsigned short)(u >> 16);
}

__device__ inline bf16x8 pack_bf8(f32x4 lo, f32x4 hi) {
  bf16x8 r;
  r[0] = (short)f2bf(lo[0]); r[1] = (short)f2bf(lo[1]);
  r[2] = (short)f2bf(lo[2]); r[3] = (short)f2bf(lo[3]);
  r[4] = (short)f2bf(hi[0]); r[5] = (short)f2bf(hi[1]);
  r[6] = (short)f2bf(hi[2]); r[7] = (short)f2bf(hi[3]);
  return r;
}

__device__ inline void gload_lds16(const void* g, void* l) {
  __builtin_amdgcn_global_load_lds(
      (const __attribute__((address_space(1))) void*)g,
      (__attribute__((address_space(3))) void*)l, 16, 0, 0);
}

// W fp32 [409][4096] -> bf16 [448][4096] in ws, zero rows 409..447
__global__ __launch_bounds__(256) void convert_w(const float* __restrict__ Wf,
                                                 unsigned short* __restrict__ Wb) {
  const int gt = blockIdx.x * 256 + threadIdx.x;
  const int row = gt >> 9;
  const int c8 = (gt & 511) << 3;
  u16x8 o;
  if (row < NS) {
    const f32x4 lo = *(const f32x4*)(Wf + (size_t)row * K_TOT + c8);
    const f32x4 hi = *(const f32x4*)(Wf + (size_t)row * K_TOT + c8 + 4);
    o = (u16x8)pack_bf8(lo, hi);
  } else {
#pragma unroll
    for (int i = 0; i < 8; ++i) o[i] = 0;
  }
  *(u16x8*)(Wb + (size_t)row * K_TOT + c8) = o;
}

// 256 blocks x 256 threads (4 waves). Wave tile 64x112 (mrep=4, nrep=7).
// A: reg-staged 2 tiles ahead -> bf16 -> swizzled ds_write. B: global_load_lds.
template <bool PRECONV>
__global__ __launch_bounds__(256, 1) void gemm_fused(
    const float* __restrict__ X, const float* __restrict__ Wf,
    const unsigned short* __restrict__ Wb, const int* __restrict__ idx,
    float* __restrict__ OUT) {
  extern __shared__ char smem[];
  char* const B0 = smem;
  char* const B1 = smem + BS_BYTES;
  char* const A0 = smem + 2 * BS_BYTES;
  char* const A1 = smem + 2 * BS_BYTES + AS_BYTES;

  const int tid = threadIdx.x;
  const int lane = tid & 63;
  const int wv = tid >> 6;   // 0..3 = wn (column quarter); all waves cover all 64 rows
  const int l16 = lane & 15;
  const int kg = lane >> 4;  // 0..3
  const int row0 = blockIdx.x * BM;

  const int arow = tid >> 2;      // A-staging: row 0..63
  const int akseg = tid & 3;      // 16-float segment within BK

  int cidx[7];
#pragma unroll
  for (int j = 0; j < 7; ++j) {
    const int n = wv * 112 + j * 16 + l16;
    cidx[j] = (n < NS) ? idx[n] : -1;
  }

  f32x4 acc[4][7] = {};
  f32x4 rg0[4], rg1[4];

  // ---- B staging: 56 x 1KB chunks, 14 per wave; LDS linear dest,
  // pre-swizzled source (phys = row*128 + ((slot ^ (row&7))<<4)) ----
  auto stageB = [&](int t, char* Bb) {
    if (PRECONV) {
#pragma unroll
      for (int c = 0; c < 14; ++c) {
        const int q = wv * 14 + c;
        const int lin = q * 1024 + lane * 16;
        const int row = lin >> 7;
        const int lw = (lin & 127) ^ ((row & 7) << 4);
        const unsigned short* src = Wb + (size_t)row * K_TOT + t * BK + (lw >> 1);
        gload_lds16(src, Bb + q * 1024);
      }
    } else {
#pragma unroll
      for (int c = 0; c < 14; ++c) {
        const int id = c * 256 + tid;   // 448 rows x 8 slots
        const int row = id >> 3, sl = id & 7;
        f32x4 lo = {}, hi = {};
        if (row < NS) {
          const float* s = Wf + (size_t)row * K_TOT + t * BK + sl * 8;
          lo = *(const f32x4*)s;
          hi = *(const f32x4*)(s + 4);
        }
        *(bf16x8*)(Bb + row * 128 + ((sl ^ (row & 7)) << 4)) = pack_bf8(lo, hi);
      }
    }
  };

  // ---- A fill: 4 global f32x4 into regs (issued 2 tiles ahead) ----
  auto fillA = [&](int t, f32x4* r) {
    const float* s = X + (size_t)(row0 + arow) * K_TOT + (t & 63) * BK + akseg * 16;
    r[0] = *(const f32x4*)(s + 0);
    r[1] = *(const f32x4*)(s + 4);
    r[2] = *(const f32x4*)(s + 8);
    r[3] = *(const f32x4*)(s + 12);
  };
  // ---- A pack+write: 16 f32 -> 2x bf16x8, swizzled slots 2*akseg, 2*akseg+1 ----
  auto packA = [&](char* Ab, const f32x4* r) {
    const int c0 = akseg * 2;
    *(bf16x8*)(Ab + arow * 128 + (((c0) ^ (arow & 7)) << 4)) = pack_bf8(r[0], r[1]);
    *(bf16x8*)(Ab + arow * 128 + (((c0 + 1) ^ (arow & 7)) << 4)) = pack_bf8(r[2], r[3]);
  };

  auto compute = [&](const char* Ab, const char* Bb) {
#pragma unroll
    for (int ks = 0; ks < 2; ++ks) {
      bf16x8 af[4];
#pragma unroll
      for (int i = 0; i < 4; ++i) {
        const int m = i * 16 + l16;
        af[i] = *(const bf16x8*)(Ab + m * 128 + ((((ks << 2) | kg) ^ (m & 7)) << 4));
      }
      bf16x8 bfr[7];
#pragma unroll
      for (int j = 0; j < 7; ++j) {
        const int n = wv * 112 + j * 16 + l16;
        bfr[j] = *(const bf16x8*)(Bb + n * 128 + ((((ks << 2) | kg) ^ (n & 7)) << 4));
      }
#pragma unroll
      for (int i = 0; i < 4; ++i)
#pragma unroll
        for (int j = 0; j < 7; ++j)
          acc[i][j] = __builtin_amdgcn_mfma_f32_16x16x32_bf16(af[i], bfr[j],
                                                              acc[i][j], 0, 0, 0);
    }
  };

  // ---- prologue ----
  stageB(0, B0);        // 14 loads
  fillA(0, rg0);        // 4
  fillA(1, rg1);        // 4
  VMWAIT(4);            // rg0 + B0 drained; rg1 in flight
  packA(A0, rg0);

  // ---- main loop, unrolled x2 for static reg-set / buffer indexing ----
  // Per half-iter: stage B(t+1); fill A(t+2); vmcnt(18) [drains B(t), A-regs(t+1)];
  // pack A(t+1); lgkm0; BAR; compute(t); BAR.  B(t+1)/A(t+2) fly across compute.
#pragma unroll 1
  for (int t = 0; t < NT; t += 2) {
    // even t
    stageB((t + 1) & 63, B1);
    fillA(t + 2, rg0);
    VMWAIT(18);
    packA(A1, rg1);
    LGKM0();
    BAR();
    compute(A0, B0);
    BAR();
    // odd t+1
    stageB((t + 2) & 63, B0);
    fillA(t + 3, rg1);
    VMWAIT(18);
    packA(A0, rg0);
    LGKM0();
    BAR();
    compute(A1, B1);
    BAR();
  }
  FULLWAIT();   // drain tail dummy DMAs before smem reuse
  BAR();

  // ---- fused epilogue: compose full rows in LDS (8 rows/pass), write coalesced ----
  float* rowbuf = (float*)smem;  // 8 x 4096 f32 = 128 KB
#pragma unroll
  for (int rb = 0; rb < 8; ++rb) {
#pragma unroll
    for (int z = 0; z < 32; ++z) {
      f32x4 zv = {};
      *(f32x4*)(rowbuf + z * 1024 + tid * 4) = zv;
    }
    __syncthreads();
    // rows r = i*16 + kg*4 + q ; r in [8rb,8rb+8) <=> i==rb>>1 && (kg>>1)==(rb&1)
    if ((kg >> 1) == (rb & 1)) {
#pragma unroll
      for (int q = 0; q < 4; ++q) {
        float* dst = rowbuf + (((kg & 1) << 2) + q) * N_COLS;
#pragma unroll
        for (int j = 0; j < 7; ++j)
          if (cidx[j] >= 0) dst[cidx[j]] = acc[rb >> 1][j][q];
      }
    }
    __syncthreads();
    float* ob = OUT + (size_t)(row0 + rb * 8) * N_COLS;
#pragma unroll
    for (int z = 0; z < 32; ++z) {
      const int off = z * 1024 + tid * 4;
      *(f32x4*)(ob + off) = *(const f32x4*)(rowbuf + off);
    }
    __syncthreads();
  }
}

extern "C" void kernel_launch(void* const* d_in, const int* in_sizes, int n_in,
                              void* d_out, int out_size, void* d_ws, size_t ws_size,
                              hipStream_t stream) {
  const float* x = (const float*)d_in[0];
  const float* w = (const float*)d_in[2];
  const int* idx = (const int*)d_in[3];
  float* out = (float*)d_out;

  const size_t need = (size_t)NP * K_TOT * 2;
  if (ws_size >= need) {
    unsigned short* wb = (unsigned short*)d_ws;
    convert_w<<<NP * K_TOT / 8 / 256, 256, 0, stream>>>(w, wb);
    hipFuncSetAttribute(reinterpret_cast<const void*>(&gemm_fused<true>),
                        hipFuncAttributeMaxDynamicSharedMemorySize, LDS_TOTAL);
    gemm_fused<true><<<M_TOT / BM, 256, LDS_TOTAL, stream>>>(x, w, wb, idx, out);
  } else {
    hipFuncSetAttribute(reinterpret_cast<const void*>(&gemm_fused<false>),
                        hipFuncAttributeMaxDynamicSharedMemorySize, LDS_TOTAL);
    gemm_fused<false><<<M_TOT / BM, 256, LDS_TOTAL, stream>>>(x, w, nullptr, idx, out);
  }
}